// Round 3
// baseline (38824.191 us; speedup 1.0000x reference)
//
#include <hip/hip_runtime.h>
#include <hip/hip_bf16.h>
#include <cstdint>

// Problem constants: B=32, T=512, N_IN=64, H=512
#define BB 32
#define TT 512
#define NIN 64
#define HH 512
#define G4 2048            // 4*H
#define BH (BB*HH)         // 16384
#define BG (BB*G4)         // 65536
#define NWG 256
#define NTHR 512

typedef _Float16 h16;
typedef _Float16 half4v __attribute__((ext_vector_type(4)));
typedef _Float16 half8v __attribute__((ext_vector_type(8)));

__device__ __forceinline__ float4 ld4f(const float* p) { return *(const float4*)p; }
__device__ __forceinline__ float4 ld4f(const h16* p) {
    half4v v = *(const half4v*)p;
    return float4{(float)v[0], (float)v[1], (float)v[2], (float)v[3]};
}
__device__ __forceinline__ void st1(float* p, float v) { *p = v; }
__device__ __forceinline__ void st1(h16* p, float v) { *p = (h16)v; }

// ---------------------------------------------------------------------------
// Two-level grid barrier, monotonic counters (no resets -> race-free).
// bar[0..7]: group counters (32 WGs each), bar[8]: root, bar[9]: generation.
// ---------------------------------------------------------------------------
__device__ __forceinline__ void gbar(int* __restrict__ bar, int target) {
    __syncthreads();   // all WG stores drained (compiler emits waitcnt before s_barrier)
    if (threadIdx.x == 0) {
        __threadfence();                        // release: L2 writeback (agent scope)
        int g = blockIdx.x >> 5;
        int a = atomicAdd(&bar[g], 1);
        if ((a & 31) == 31) {                   // last of my 32-WG group this round
            int r = atomicAdd(&bar[8], 1);
            if ((r & 7) == 7) atomicAdd(&bar[9], 1);   // full barrier -> bump gen
        }
        long it = 0;
        while (__hip_atomic_load(&bar[9], __ATOMIC_RELAXED, __HIP_MEMORY_SCOPE_AGENT) < target) {
            if (++it > (1L << 20)) break;       // hang guard (never hit if logic correct)
            __builtin_amdgcn_s_sleep(2);
        }
        __threadfence();                        // acquire: invalidate stale L1/L2
    }
    __syncthreads();
}

// ---------------------------------------------------------------------------
// Transpose [R][C] -> [C][R] fp32
// ---------------------------------------------------------------------------
__global__ void transpose_k(const float* __restrict__ in, float* __restrict__ out,
                            int R, int C) {
    __shared__ float t[32][33];
    int bx = blockIdx.x, by = blockIdx.y;
    int x = threadIdx.x, y = threadIdx.y;  // 32 x 8
    for (int i = 0; i < 32; i += 8)
        t[y + i][x] = in[(size_t)(by * 32 + y + i) * C + bx * 32 + x];
    __syncthreads();
    for (int i = 0; i < 32; i += 8)
        out[(size_t)(bx * 32 + y + i) * R + by * 32 + x] = t[x][y + i];
}

// x [B][T][NIN] -> xt [T][B][NIN]
__global__ void permute_x_k(const float* __restrict__ x, float* __restrict__ xt) {
    int idx = blockIdx.x * 256 + threadIdx.x;       // over T*B*16 float4s
    int q = idx & 15, bt = idx >> 4;                // bt = t*32 + b
    int t = bt >> 5, b = bt & 31;
    ((float4*)xt)[idx] = ((const float4*)x)[((size_t)b * TT + t) * 16 + q];
}

// ---------------------------------------------------------------------------
// C[M][N] = A[M][K] @ B[K][N] (+bias1[n]+bias2[n]); A,B row-major, B fp32.
// out_mode 0: C + m*N.  out_mode 1: row m=(t*32+b) scatters to C+((b*T+t))*N.
// ---------------------------------------------------------------------------
#define GBM 128
#define GBN 64
#define GBK 32
template <typename AT, typename CT>
__global__ __launch_bounds__(256) void gemm_k(
    const AT* __restrict__ A, const float* __restrict__ B,
    CT* __restrict__ C, int M, int N, int K,
    const float* __restrict__ bias1, const float* __restrict__ bias2,
    int out_mode) {
    __shared__ float As[GBM][GBK + 4];
    __shared__ float Bs[GBK][GBN + 4];
    int bm = blockIdx.x, bn = blockIdx.y;
    int tid = threadIdx.x;
    int tx = tid & 15, ty = tid >> 4;
    const AT* Ab = A + (size_t)bm * GBM * K;
    const float* Bb = B + (size_t)bn * GBN;
    float acc[8][4];
#pragma unroll
    for (int i = 0; i < 8; ++i)
#pragma unroll
        for (int j = 0; j < 4; ++j) acc[i][j] = 0.f;

    for (int k0 = 0; k0 < K; k0 += GBK) {
#pragma unroll
        for (int l = 0; l < 4; ++l) {
            int idx = l * 256 + tid;
            int r = idx >> 3, c4 = idx & 7;
            *(float4*)&As[r][c4 * 4] = ld4f(Ab + (size_t)r * K + k0 + c4 * 4);
        }
#pragma unroll
        for (int l = 0; l < 2; ++l) {
            int idx = l * 256 + tid;
            int r = idx >> 4, c4 = idx & 15;
            *(float4*)&Bs[r][c4 * 4] = *(const float4*)(Bb + (size_t)(k0 + r) * N + c4 * 4);
        }
        __syncthreads();
#pragma unroll
        for (int k = 0; k < GBK; ++k) {
            float a[8];
#pragma unroll
            for (int i = 0; i < 8; ++i) a[i] = As[ty * 8 + i][k];
            float4 b4 = *(float4*)&Bs[k][tx * 4];
            float bbv[4] = {b4.x, b4.y, b4.z, b4.w};
#pragma unroll
            for (int i = 0; i < 8; ++i)
#pragma unroll
                for (int j = 0; j < 4; ++j) acc[i][j] += a[i] * bbv[j];
        }
        __syncthreads();
    }
    float badd[4];
#pragma unroll
    for (int j = 0; j < 4; ++j) {
        int n = bn * GBN + tx * 4 + j;
        badd[j] = (bias1 ? bias1[n] : 0.f) + (bias2 ? bias2[n] : 0.f);
    }
#pragma unroll
    for (int i = 0; i < 8; ++i) {
        int m = bm * GBM + ty * 8 + i;
        CT* Crow;
        if (out_mode == 0) Crow = C + (size_t)m * N;
        else               Crow = C + ((size_t)(m & 31) * TT + (m >> 5)) * N;
#pragma unroll
        for (int j = 0; j < 4; ++j)
            st1(&Crow[bn * GBN + tx * 4 + j], acc[i][j] + badd[j]);
    }
}

// ---------------------------------------------------------------------------
// Persistent pipelined FORWARD. 256 WGs x 512 thr.
// WG (layer = wid>>7, rslot = wid&127) owns j-set {4*rslot..4*rslot+3} ->
// 16 gate-rows {q*512 + j}. W slice resident in LDS for all 512 steps.
// Layer0 step t=s (s<512); layer1 step t=s-1 (s>=1): g = [W_ih1|W_hh1]·[h0(t);h1(t-1)].
// c lives in LDS for the whole sequence. Lane=(b, k-half); 16-row register acc.
// ---------------------------------------------------------------------------
__global__ __launch_bounds__(NTHR, 1) void fwd_persist(
    const float* __restrict__ W_hh0, const float* __restrict__ W_ih1,
    const float* __restrict__ W_hh1,
    const float* __restrict__ b_ih1, const float* __restrict__ b_hh1,
    h16* __restrict__ G0, h16* __restrict__ G1,
    h16* __restrict__ C0h, h16* __restrict__ C1h,
    h16* __restrict__ H0p, h16* __restrict__ H1p,   // [2][BB][HH] ping-pong
    int* __restrict__ bar)
{
    __shared__ float Wlds[16][1024];     // 64KB: layer0 uses [.][0..512)
    __shared__ float red[8][16][32];     // 16KB cross-wave partials
    __shared__ float pre[16][32];        // 2KB preactivations
    __shared__ float c_l[4][32];         // persistent cell state (own j x b)
    __shared__ float bias_l[16];

    const int tid = threadIdx.x;
    const int wid = blockIdx.x;
    const int layer = wid >> 7;
    const int rslot = wid & 127;
    const int j0 = rslot * 4;
    const int wv = tid >> 6, lane = tid & 63, b = lane & 31, half = lane >> 5;

    if (layer == 0) {
        for (int idx = tid; idx < 2048; idx += NTHR) {        // 16 rows x 128 f4
            int r = idx >> 7, c4 = idx & 127;
            int row = (r >> 2) * HH + j0 + (r & 3);
            *(float4*)&Wlds[r][c4 * 4] = *(const float4*)(W_hh0 + (size_t)row * HH + c4 * 4);
        }
    } else {
        for (int idx = tid; idx < 2048; idx += NTHR) {
            int r = idx >> 7, c4 = idx & 127;
            int row = (r >> 2) * HH + j0 + (r & 3);
            *(float4*)&Wlds[r][c4 * 4]       = *(const float4*)(W_ih1 + (size_t)row * HH + c4 * 4);
            *(float4*)&Wlds[r][512 + c4 * 4] = *(const float4*)(W_hh1 + (size_t)row * HH + c4 * 4);
        }
        if (tid < 16) {
            int row = (tid >> 2) * HH + j0 + (tid & 3);
            bias_l[tid] = b_ih1[row] + b_hh1[row];
        }
    }
    __syncthreads();

#pragma unroll 1
    for (int s = 0; s <= TT; ++s) {
        const int t = (layer == 0) ? s : s - 1;
        const bool active = (layer == 0) ? (s < TT) : (s >= 1);
        int KB = 0;
        if (active) {
            const h16* hsrc0;
            const h16* hsrc1 = nullptr;
            if (layer == 0) {
                KB = (t > 0) ? 32 : 0;
                hsrc0 = H0p + (size_t)((t - 1) & 1) * BH;
            } else {
                KB = (t > 0) ? 64 : 32;
                hsrc0 = H0p + (size_t)(t & 1) * BH;          // h0(t)
                hsrc1 = H1p + (size_t)((t - 1) & 1) * BH;    // h1(t-1)
            }
            if (KB) {
                float acc[16];
#pragma unroll
                for (int r = 0; r < 16; ++r) acc[r] = 0.f;
                for (int kb = wv; kb < KB; kb += 8) {
                    int k0 = kb * 16 + half * 8;
                    const h16* src = (k0 < 512) ? (hsrc0 + b * HH + k0)
                                                : (hsrc1 + b * HH + (k0 - 512));
                    half8v hv = *(const half8v*)src;
                    float hf[8];
#pragma unroll
                    for (int i = 0; i < 8; ++i) hf[i] = (float)hv[i];
#pragma unroll
                    for (int r = 0; r < 16; ++r) {
                        const float* wr = &Wlds[r][k0];
                        float4 wa = *(const float4*)wr;
                        float4 wb = *(const float4*)(wr + 4);
                        acc[r] += hf[0]*wa.x + hf[1]*wa.y + hf[2]*wa.z + hf[3]*wa.w
                                + hf[4]*wb.x + hf[5]*wb.y + hf[6]*wb.z + hf[7]*wb.w;
                    }
                }
#pragma unroll
                for (int r = 0; r < 16; ++r) acc[r] += __shfl_xor(acc[r], 32);
#pragma unroll
                for (int rr = 0; rr < 8; ++rr) {             // each half writes 8 rows
                    int r = half * 8 + rr;
                    red[wv][r][b] = acc[r];
                }
            }
            __syncthreads();
            {   // gather: 512 threads, one (gate-row r, b) each
                int r = tid >> 5, bb = tid & 31;
                int q = r >> 2, jj = r & 3;
                int row = q * HH + j0 + jj;
                float sum = 0.f;
                if (KB) {
#pragma unroll
                    for (int w = 0; w < 8; ++w) sum += red[w][r][bb];
                }
                if (layer == 0) sum += (float)G0[(size_t)t * BG + bb * G4 + row];
                else            sum += bias_l[r];
                pre[r][bb] = sum;
            }
            __syncthreads();
            if (tid < 128) {   // pointwise: (jj, b)
                int jj = tid >> 5, bb = tid & 31;
                int j = j0 + jj;
                float gi = pre[jj][bb],      gf = pre[4 + jj][bb];
                float gg = pre[8 + jj][bb],  go = pre[12 + jj][bb];
                float i_ = 1.f / (1.f + expf(-gi));
                float f_ = 1.f / (1.f + expf(-gf));
                float g_ = tanhf(gg);
                float o_ = 1.f / (1.f + expf(-go));
                float cp = (t > 0) ? c_l[jj][bb] : 0.f;
                float c = f_ * cp + i_ * g_;
                float h = o_ * tanhf(c);
                c_l[jj][bb] = c;
                h16* Gt = (layer == 0 ? G0 : G1) + (size_t)t * BG + bb * G4;
                Gt[j]          = (h16)i_;
                Gt[HH + j]     = (h16)f_;
                Gt[2 * HH + j] = (h16)g_;
                Gt[3 * HH + j] = (h16)o_;
                (layer == 0 ? C0h : C1h)[(size_t)t * BH + bb * HH + j] = (h16)c;
                ((layer == 0 ? H0p : H1p) + (size_t)(t & 1) * BH)[bb * HH + j] = (h16)h;
            }
        }
        gbar(bar, s + 1);
    }
}

// ---------------------------------------------------------------------------
// Persistent pipelined BACKWARD. grp0 (wid<128): layer1-bwd t1=511-s (s<512);
// grp1: layer0-bwd t0=512-s (s>=1), fusing dh0_ext = dG1(t0)@W_ih1^T.
// dG overwrites gates slab in place; dc persistent in LDS.
// ---------------------------------------------------------------------------
__device__ __forceinline__ void bwd_dot_range(
    const h16* __restrict__ slab, const float (*Wlds)[4096], int wofs,
    int wv, int half, int b, float acc[4])
{
    for (int kb = wv; kb < 128; kb += 8) {
        int k0 = kb * 16 + half * 8;
        half8v hv = *(const half8v*)(slab + b * G4 + k0);
        float hf[8];
#pragma unroll
        for (int i = 0; i < 8; ++i) hf[i] = (float)hv[i];
#pragma unroll
        for (int jr = 0; jr < 4; ++jr) {
            const float* wr = &Wlds[jr][wofs + k0];
            float4 wa = *(const float4*)wr;
            float4 wb = *(const float4*)(wr + 4);
            acc[jr] += hf[0]*wa.x + hf[1]*wa.y + hf[2]*wa.z + hf[3]*wa.w
                     + hf[4]*wb.x + hf[5]*wb.y + hf[6]*wb.z + hf[7]*wb.w;
        }
    }
}

__global__ __launch_bounds__(NTHR, 1) void bwd_persist(
    const float* __restrict__ WT_HH0, const float* __restrict__ WT_HH1,
    const float* __restrict__ WT_IH1, const float* __restrict__ W_out,
    h16* __restrict__ G0, h16* __restrict__ G1,
    const h16* __restrict__ C0h, const h16* __restrict__ C1h,
    int* __restrict__ bar)
{
    __shared__ float Wlds[4][4096];      // 64KB: grp0 uses [.][0..2048)
    __shared__ float red[8][4][32];      // 4KB
    __shared__ float dc_l[4][32];        // persistent dc (own j x b)
    __shared__ float wout_l[4];

    const int tid = threadIdx.x, wid = blockIdx.x;
    const bool isL1 = (wid >> 7) == 0;
    const int rslot = wid & 127, j0 = rslot * 4;
    const int wv = tid >> 6, lane = tid & 63, b = lane & 31, half = lane >> 5;

    if (isL1) {
        for (int idx = tid; idx < 2048; idx += NTHR) {       // 4 rows x 512 f4
            int jr = idx >> 9, c4 = idx & 511;
            *(float4*)&Wlds[jr][c4 * 4] = *(const float4*)(WT_HH1 + (size_t)(j0 + jr) * G4 + c4 * 4);
        }
        if (tid < 4) wout_l[tid] = W_out[j0 + tid];
    } else {
        for (int idx = tid; idx < 2048; idx += NTHR) {
            int jr = idx >> 9, c4 = idx & 511;
            *(float4*)&Wlds[jr][c4 * 4]        = *(const float4*)(WT_HH0 + (size_t)(j0 + jr) * G4 + c4 * 4);
            *(float4*)&Wlds[jr][2048 + c4 * 4] = *(const float4*)(WT_IH1 + (size_t)(j0 + jr) * G4 + c4 * 4);
        }
    }
    __syncthreads();

#pragma unroll 1
    for (int s = 0; s <= TT; ++s) {
        const int t = isL1 ? (511 - s) : (512 - s);
        const bool active = isL1 ? (s < TT) : (s >= 1);
        if (active) {
            float acc[4] = {0.f, 0.f, 0.f, 0.f};
            bool didDot = false;
            if (isL1) {
                if (t < 511) { bwd_dot_range(G1 + (size_t)(t + 1) * BG, Wlds, 0, wv, half, b, acc); didDot = true; }
            } else {
                if (t < 511) { bwd_dot_range(G0 + (size_t)(t + 1) * BG, Wlds, 0, wv, half, b, acc); }
                bwd_dot_range(G1 + (size_t)t * BG, Wlds, 2048, wv, half, b, acc);
                didDot = true;
            }
            if (didDot) {
#pragma unroll
                for (int jr = 0; jr < 4; ++jr) acc[jr] += __shfl_xor(acc[jr], 32);
#pragma unroll
                for (int rr = 0; rr < 2; ++rr) {
                    int jr = half * 2 + rr;
                    red[wv][jr][b] = acc[jr];
                }
            }
            __syncthreads();
            if (tid < 128) {   // gather + pointwise: (jr, b)
                int jr = tid >> 5, bb = tid & 31;
                int j = j0 + jr;
                float dh = 0.f;
                if (didDot) {
#pragma unroll
                    for (int w = 0; w < 8; ++w) dh += red[w][jr][bb];
                }
                if (isL1) dh += wout_l[jr];
                h16* Gt = (isL1 ? G1 : G0) + (size_t)t * BG + bb * G4;
                const h16* Ch = isL1 ? C1h : C0h;
                float i_ = (float)Gt[j];
                float f_ = (float)Gt[HH + j];
                float g_ = (float)Gt[2 * HH + j];
                float o_ = (float)Gt[3 * HH + j];
                float c  = (float)Ch[(size_t)t * BH + bb * HH + j];
                float cp = (t > 0) ? (float)Ch[(size_t)(t - 1) * BH + bb * HH + j] : 0.f;
                float th = tanhf(c);
                float dc_in = (t < 511) ? dc_l[jr][bb] : 0.f;
                float do_ = dh * th;
                float dc = dc_in + dh * o_ * (1.f - th * th);
                float di = dc * g_, df = dc * cp, dg = dc * i_;
                Gt[j]          = (h16)(di * i_ * (1.f - i_));
                Gt[HH + j]     = (h16)(df * f_ * (1.f - f_));
                Gt[2 * HH + j] = (h16)(dg * (1.f - g_ * g_));
                Gt[3 * HH + j] = (h16)(do_ * o_ * (1.f - o_));
                dc_l[jr][bb] = dc * f_;
            }
        }
        gbar(bar + 16, s + 1);
    }
}

// ---------------------------------------------------------------------------
extern "C" void kernel_launch(void* const* d_in, const int* in_sizes, int n_in,
                              void* d_out, int out_size, void* d_ws, size_t ws_size,
                              hipStream_t stream) {
    const float* x     = (const float*)d_in[0];
    const float* W_ih0 = (const float*)d_in[1];
    const float* W_hh0 = (const float*)d_in[2];
    const float* b_ih0 = (const float*)d_in[3];
    const float* b_hh0 = (const float*)d_in[4];
    const float* W_ih1 = (const float*)d_in[5];
    const float* W_hh1 = (const float*)d_in[6];
    const float* b_ih1 = (const float*)d_in[7];
    const float* b_hh1 = (const float*)d_in[8];
    const float* W_out = (const float*)d_in[9];
    float* out = (float*)d_out;

    // ---- workspace layout (~177 MB) ----
    char* p = (char*)d_ws;
    auto alloc = [&](size_t bytes) { char* r = p; p += (bytes + 255) & ~(size_t)255; return r; };
    h16*  G0     = (h16*)alloc((size_t)TT * BG * 2);   // xg0 -> gates0 -> dG0
    h16*  G1     = (h16*)alloc((size_t)TT * BG * 2);   // gates1 -> dG1
    h16*  C0h    = (h16*)alloc((size_t)TT * BH * 2);
    h16*  C1h    = (h16*)alloc((size_t)TT * BH * 2);
    h16*  H0p    = (h16*)alloc((size_t)2 * BH * 2);
    h16*  H1p    = (h16*)alloc((size_t)2 * BH * 2);
    float* XT     = (float*)alloc((size_t)TT * BB * NIN * 4);
    float* WT_IH0 = (float*)alloc((size_t)NIN * G4 * 4);
    float* WT_HH0 = (float*)alloc((size_t)HH * G4 * 4);
    float* WT_HH1 = (float*)alloc((size_t)HH * G4 * 4);
    float* WT_IH1 = (float*)alloc((size_t)HH * G4 * 4);
    int*   bar    = (int*)alloc(32 * sizeof(int));
    if ((size_t)(p - (char*)d_ws) > ws_size) return;   // visible failure if ws too small

    hipMemsetAsync(bar, 0, 32 * sizeof(int), stream);

    dim3 tb(32, 8);
    permute_x_k<<<1024, 256, 0, stream>>>(x, XT);
    transpose_k<<<dim3(NIN / 32, G4 / 32), tb, 0, stream>>>(W_ih0, WT_IH0, G4, NIN);
    transpose_k<<<dim3(HH / 32, G4 / 32), tb, 0, stream>>>(W_hh0, WT_HH0, G4, HH);
    transpose_k<<<dim3(HH / 32, G4 / 32), tb, 0, stream>>>(W_hh1, WT_HH1, G4, HH);
    transpose_k<<<dim3(HH / 32, G4 / 32), tb, 0, stream>>>(W_ih1, WT_IH1, G4, HH);

    // xg0 = XT @ W_ih0^T + b_ih0 + b_hh0   [16384 x 2048], K=64 (out fp16)
    gemm_k<float, h16><<<dim3(TT * BB / GBM, G4 / GBN), 256, 0, stream>>>(
        XT, WT_IH0, G0, TT * BB, G4, NIN, b_ih0, b_hh0, 0);

    fwd_persist<<<NWG, NTHR, 0, stream>>>(
        W_hh0, W_ih1, W_hh1, b_ih1, b_hh1,
        G0, G1, C0h, C1h, H0p, H1p, bar);

    bwd_persist<<<NWG, NTHR, 0, stream>>>(
        WT_HH0, WT_HH1, WT_IH1, W_out,
        G0, G1, C0h, C1h, bar);

    // dx = dG0 @ W_ih0  [16384 x 64], K=2048 -> scatter to out [B][T][NIN]
    gemm_k<h16, float><<<dim3(TT * BB / GBM, NIN / GBN), 256, 0, stream>>>(
        G0, W_ih0, out, TT * BB, NIN, G4, nullptr, nullptr, 1);
}

// Round 5
// 18188.029 us; speedup vs baseline: 2.1346x; 2.1346x over previous
//
#include <hip/hip_runtime.h>
#include <hip/hip_bf16.h>
#include <cstdint>

// Problem constants: B=32, T=512, N_IN=64, H=512
#define BB 32
#define TT 512
#define NIN 64
#define HH 512
#define G4 2048            // 4*H
#define BH (BB*HH)         // 16384
#define BG (BB*G4)         // 65536
#define NWG 256
#define NTHR 512
#define CSTR 16            // counter stride (ints) -> 64B per step

typedef _Float16 h16;
typedef _Float16 half4v __attribute__((ext_vector_type(4)));
typedef _Float16 half8v __attribute__((ext_vector_type(8)));
typedef uint32_t uv2 __attribute__((ext_vector_type(2)));
typedef uint32_t uv4 __attribute__((ext_vector_type(4)));

__device__ __forceinline__ float4 ld4f(const float* p) { return *(const float4*)p; }
__device__ __forceinline__ float4 ld4f(const h16* p) {
    half4v v = *(const half4v*)p;
    return float4{(float)v[0], (float)v[1], (float)v[2], (float)v[3]};
}
__device__ __forceinline__ void st1(float* p, float v) { *p = v; }
__device__ __forceinline__ void st1(h16* p, float v) { *p = (h16)v; }

// ---- device-coherent (MALL) access helpers: sc0 sc1 bypass non-coherent L1/L2 ----
__device__ __forceinline__ void dc_issue8(const void* p, uv4* o) {
    asm volatile(
        "global_load_dwordx4 %0, %8, off sc0 sc1\n\t"
        "global_load_dwordx4 %1, %8, off offset:256 sc0 sc1\n\t"
        "global_load_dwordx4 %2, %8, off offset:512 sc0 sc1\n\t"
        "global_load_dwordx4 %3, %8, off offset:768 sc0 sc1\n\t"
        "global_load_dwordx4 %4, %8, off offset:1024 sc0 sc1\n\t"
        "global_load_dwordx4 %5, %8, off offset:1280 sc0 sc1\n\t"
        "global_load_dwordx4 %6, %8, off offset:1536 sc0 sc1\n\t"
        "global_load_dwordx4 %7, %8, off offset:1792 sc0 sc1"
        : "=&v"(o[0]), "=&v"(o[1]), "=&v"(o[2]), "=&v"(o[3]),
          "=&v"(o[4]), "=&v"(o[5]), "=&v"(o[6]), "=&v"(o[7])
        : "v"(p) : "memory");
}
__device__ __forceinline__ void vm_wait0() {
    asm volatile("s_waitcnt vmcnt(0)" ::: "memory");
    __builtin_amdgcn_sched_barrier(0);   // rule 18: keep dependent code below the wait
}
__device__ __forceinline__ void st8_dc(void* p, uv2 v) {
    asm volatile("global_store_dwordx2 %0, %1, off sc0 sc1" :: "v"(p), "v"(v) : "memory");
}
__device__ __forceinline__ void st16_dc(void* p, uv4 v) {
    asm volatile("global_store_dwordx4 %0, %1, off sc0 sc1" :: "v"(p), "v"(v) : "memory");
}

// ---- flag sync: monotonic per-step counters, relaxed agent atomics ----
__device__ __forceinline__ void wait_ge(int* c, int target) {
    if (threadIdx.x == 0) {
        long it = 0;
        while (__hip_atomic_load(c, __ATOMIC_RELAXED, __HIP_MEMORY_SCOPE_AGENT) < target) {
            __builtin_amdgcn_s_sleep(4);
            if (++it > (1L << 20)) break;   // hang guard -> wrong result, not hang
        }
    }
    __syncthreads();
}

// ---------------------------------------------------------------------------
// Transpose [R][C] -> [C][R] fp32
// ---------------------------------------------------------------------------
__global__ void transpose_k(const float* __restrict__ in, float* __restrict__ out,
                            int R, int C) {
    __shared__ float t[32][33];
    int bx = blockIdx.x, by = blockIdx.y;
    int x = threadIdx.x, y = threadIdx.y;  // 32 x 8
    for (int i = 0; i < 32; i += 8)
        t[y + i][x] = in[(size_t)(by * 32 + y + i) * C + bx * 32 + x];
    __syncthreads();
    for (int i = 0; i < 32; i += 8)
        out[(size_t)(bx * 32 + y + i) * R + by * 32 + x] = t[x][y + i];
}

// x [B][T][NIN] -> xt [T][B][NIN]
__global__ void permute_x_k(const float* __restrict__ x, float* __restrict__ xt) {
    int idx = blockIdx.x * 256 + threadIdx.x;       // over T*B*16 float4s
    int q = idx & 15, bt = idx >> 4;                // bt = t*32 + b
    int t = bt >> 5, b = bt & 31;
    ((float4*)xt)[idx] = ((const float4*)x)[((size_t)b * TT + t) * 16 + q];
}

// ---------------------------------------------------------------------------
// C[M][N] = A[M][K] @ B[K][N] (+bias1[n]+bias2[n]); A,B row-major, B fp32.
// out_mode 0: C + m*N.  out_mode 1: row m=(t*32+b) scatters to C+((b*T+t))*N.
// ---------------------------------------------------------------------------
#define GBM 128
#define GBN 64
#define GBK 32
template <typename AT, typename CT>
__global__ __launch_bounds__(256) void gemm_k(
    const AT* __restrict__ A, const float* __restrict__ B,
    CT* __restrict__ C, int M, int N, int K,
    const float* __restrict__ bias1, const float* __restrict__ bias2,
    int out_mode) {
    __shared__ float As[GBM][GBK + 4];
    __shared__ float Bs[GBK][GBN + 4];
    int bm = blockIdx.x, bn = blockIdx.y;
    int tid = threadIdx.x;
    int tx = tid & 15, ty = tid >> 4;
    const AT* Ab = A + (size_t)bm * GBM * K;
    const float* Bb = B + (size_t)bn * GBN;
    float acc[8][4];
#pragma unroll
    for (int i = 0; i < 8; ++i)
#pragma unroll
        for (int j = 0; j < 4; ++j) acc[i][j] = 0.f;

    for (int k0 = 0; k0 < K; k0 += GBK) {
#pragma unroll
        for (int l = 0; l < 4; ++l) {
            int idx = l * 256 + tid;
            int r = idx >> 3, c4 = idx & 7;
            *(float4*)&As[r][c4 * 4] = ld4f(Ab + (size_t)r * K + k0 + c4 * 4);
        }
#pragma unroll
        for (int l = 0; l < 2; ++l) {
            int idx = l * 256 + tid;
            int r = idx >> 4, c4 = idx & 15;
            *(float4*)&Bs[r][c4 * 4] = *(const float4*)(Bb + (size_t)(k0 + r) * N + c4 * 4);
        }
        __syncthreads();
#pragma unroll
        for (int k = 0; k < GBK; ++k) {
            float a[8];
#pragma unroll
            for (int i = 0; i < 8; ++i) a[i] = As[ty * 8 + i][k];
            float4 b4 = *(float4*)&Bs[k][tx * 4];
            float bbv[4] = {b4.x, b4.y, b4.z, b4.w};
#pragma unroll
            for (int i = 0; i < 8; ++i)
#pragma unroll
                for (int j = 0; j < 4; ++j) acc[i][j] += a[i] * bbv[j];
        }
        __syncthreads();
    }
    float badd[4];
#pragma unroll
    for (int j = 0; j < 4; ++j) {
        int n = bn * GBN + tx * 4 + j;
        badd[j] = (bias1 ? bias1[n] : 0.f) + (bias2 ? bias2[n] : 0.f);
    }
#pragma unroll
    for (int i = 0; i < 8; ++i) {
        int m = bm * GBM + ty * 8 + i;
        CT* Crow;
        if (out_mode == 0) Crow = C + (size_t)m * N;
        else               Crow = C + ((size_t)(m & 31) * TT + (m >> 5)) * N;
#pragma unroll
        for (int j = 0; j < 4; ++j)
            st1(&Crow[bn * GBN + tx * 4 + j], acc[i][j] + badd[j]);
    }
}

// ---------------------------------------------------------------------------
// fwd dot: 8 chunks of 4 fp32 h x 16 gate rows, fp32 W in LDS.
// Lanes of a half-wave share koff -> W reads are LDS broadcasts.
// ---------------------------------------------------------------------------
__device__ __forceinline__ void fwd_comp8(const uv4* buf, const float (*W)[1024],
                                          int kbase, float acc[16]) {
#pragma unroll
    for (int i = 0; i < 8; ++i) {
        float4 h4 = __builtin_bit_cast(float4, buf[i]);
        int k0 = kbase + i * 64;
#pragma unroll
        for (int r = 0; r < 16; ++r) {
            float4 w = *(const float4*)&W[r][k0];
            acc[r] += h4.x * w.x + h4.y * w.y + h4.z * w.z + h4.w * w.w;
        }
    }
}

// ---------------------------------------------------------------------------
// Persistent pipelined FORWARD. 256 WGs x 512 thr, 1 WG/CU (LDS-limited).
// layer = wid>>7; WG owns 4 h-cols j0..j0+3 (16 gate rows). W fp32 in LDS.
// L0 does t=s; L1 does t=s-1. h handoff fp32 via sc0sc1 at MALL; per-step
// counter cntF[s] (target 256). Signals are wave-0-only after vmcnt(0).
// ---------------------------------------------------------------------------
__global__ __launch_bounds__(NTHR, 1) void fwd_persist(
    const float* __restrict__ W_hh0, const float* __restrict__ W_ih1,
    const float* __restrict__ W_hh1,
    const float* __restrict__ b_ih1, const float* __restrict__ b_hh1,
    h16* __restrict__ G0, h16* __restrict__ G1,
    h16* __restrict__ C0h, h16* __restrict__ C1h,
    float* __restrict__ H0p, float* __restrict__ H1p,   // [2][BB][HH] fp32 ping-pong
    int* __restrict__ cntF)
{
    __shared__ float Wlds[16][1024];     // 64KB fp32 (L0 uses cols 0..511)
    __shared__ float red[8][16][32];     // 16KB
    __shared__ float pre[16][32];        // 2KB
    __shared__ float c_l[4][32];         // persistent cell state
    __shared__ float h_s[4][32];
    __shared__ h16   c_s[4][32];
    __shared__ h16   g_s[16][32];
    __shared__ float bias_l[16];

    const int tid = threadIdx.x, wid = blockIdx.x;
    const int layer = wid >> 7, rslot = wid & 127, j0 = rslot * 4;
    const int wv = tid >> 6, lane = tid & 63, b = lane & 31, half = lane >> 5;
    const int koff = wv * 8 + half * 4;          // fp32 index, 16 distinct values

    if (layer == 0) {
        for (int idx = tid; idx < 2048; idx += NTHR) {   // 16 rows x 128 float4
            int r = idx >> 7, c4 = idx & 127;
            int row = (r >> 2) * HH + j0 + (r & 3);
            *(float4*)&Wlds[r][c4 * 4] = *(const float4*)(W_hh0 + (size_t)row * HH + c4 * 4);
        }
    } else {
        for (int idx = tid; idx < 4096; idx += NTHR) {   // 16 rows x 256 float4
            int r = idx >> 8, c4 = idx & 255;
            int row = (r >> 2) * HH + j0 + (r & 3);
            if (c4 < 128)
                *(float4*)&Wlds[r][c4 * 4] = *(const float4*)(W_ih1 + (size_t)row * HH + c4 * 4);
            else
                *(float4*)&Wlds[r][512 + (c4 - 128) * 4] =
                    *(const float4*)(W_hh1 + (size_t)row * HH + (c4 - 128) * 4);
        }
        if (tid < 16) {
            int row = (tid >> 2) * HH + j0 + (tid & 3);
            bias_l[tid] = b_ih1[row] + b_hh1[row];
        }
    }
    __syncthreads();

#pragma unroll 1
    for (int s = 0; s <= TT; ++s) {
        if (s > 0) wait_ge(cntF + (size_t)(s - 1) * CSTR, NWG);
        const int t = (layer == 0) ? s : s - 1;
        const bool active = (layer == 0) ? (s < TT) : (s >= 1);
        const bool haveDot = active && !(layer == 0 && t == 0);
        if (active) {
            if (haveDot) {
                float acc[16];
#pragma unroll
                for (int r = 0; r < 16; ++r) acc[r] = 0.f;
                if (layer == 0) {
                    uv4 bufA[8];
                    const char* pa = (const char*)(H0p + (size_t)((t - 1) & 1) * BH + b * HH) + koff * 4;
                    dc_issue8(pa, bufA);
                    vm_wait0();
                    fwd_comp8(bufA, Wlds, koff, acc);
                } else {
                    uv4 bufA[8], bufB[8];
                    const char* pa = (const char*)(H0p + (size_t)(t & 1) * BH + b * HH) + koff * 4;
                    dc_issue8(pa, bufA);
                    const bool hb = (t > 0);
                    if (hb) {
                        const char* pb = (const char*)(H1p + (size_t)((t - 1) & 1) * BH + b * HH) + koff * 4;
                        dc_issue8(pb, bufB);
                    }
                    vm_wait0();
                    fwd_comp8(bufA, Wlds, koff, acc);
                    if (hb) fwd_comp8(bufB, Wlds, 512 + koff, acc);
                }
#pragma unroll
                for (int r = 0; r < 16; ++r) acc[r] += __shfl_xor(acc[r], 32);
#pragma unroll
                for (int rr = 0; rr < 8; ++rr) {
                    int r = half * 8 + rr;
                    red[wv][r][b] = acc[r];
                }
            }
            __syncthreads();
            {   // gather: one (gate-row r, b) per thread
                int r = tid >> 5, bb = tid & 31;
                int row = (r >> 2) * HH + j0 + (r & 3);
                float sum = 0.f;
                if (haveDot) {
#pragma unroll
                    for (int w = 0; w < 8; ++w) sum += red[w][r][bb];
                }
                if (layer == 0) sum += (float)G0[(size_t)t * BG + bb * G4 + row];
                else            sum += bias_l[r];
                pre[r][bb] = sum;
            }
            __syncthreads();
            if (tid < 128) {   // pointwise: (jj, b)
                int jj = tid >> 5, bb = tid & 31;
                float gi = pre[jj][bb],      gf = pre[4 + jj][bb];
                float gg = pre[8 + jj][bb],  go = pre[12 + jj][bb];
                float i_ = 1.f / (1.f + expf(-gi));
                float f_ = 1.f / (1.f + expf(-gf));
                float g_ = tanhf(gg);
                float o_ = 1.f / (1.f + expf(-go));
                float cp = (t > 0) ? c_l[jj][bb] : 0.f;
                float c = f_ * cp + i_ * g_;
                float h = o_ * tanhf(c);
                c_l[jj][bb] = c;
                h_s[jj][bb] = h;
                c_s[jj][bb] = (h16)c;
                g_s[0 * 4 + jj][bb] = (h16)i_;
                g_s[1 * 4 + jj][bb] = (h16)f_;
                g_s[2 * 4 + jj][bb] = (h16)g_;
                g_s[3 * 4 + jj][bb] = (h16)o_;
            }
            __syncthreads();
            if (tid < 128) {   // gates pack: 8B normal store per (q,b) (cross-kernel data)
                int q = tid >> 5, bb = tid & 31;
                half4v gp = {g_s[q * 4 + 0][bb], g_s[q * 4 + 1][bb],
                             g_s[q * 4 + 2][bb], g_s[q * 4 + 3][bb]};
                h16* Gt = (layer == 0 ? G0 : G1) + (size_t)t * BG + bb * G4;
                *(half4v*)(Gt + q * HH + j0) = gp;
            }
            if (tid < 32) {    // c pack (normal) + h pack (sc0sc1, 16B fp32) -- wave 0 only
                half4v cpk = {c_s[0][tid], c_s[1][tid], c_s[2][tid], c_s[3][tid]};
                *(half4v*)((layer == 0 ? C0h : C1h) + (size_t)t * BH + tid * HH + j0) = cpk;
                float4 hv = {h_s[0][tid], h_s[1][tid], h_s[2][tid], h_s[3][tid]};
                st16_dc((layer == 0 ? H0p : H1p) + (size_t)(t & 1) * BH + tid * HH + j0,
                        __builtin_bit_cast(uv4, hv));
            }
            vm_wait0();        // wave0: its sc h-stores are at MALL before the signal
        }
        if (s < TT && tid == 0) atomicAdd(cntF + (size_t)s * CSTR, 1);
    }
}

// ---------------------------------------------------------------------------
// bwd dot: fp16 dG slab (sc0sc1 from MALL) x fp32 W rows in LDS, K=2048.
// 16 chunks of 8 h16 per lane, stride 256B; W reads are LDS broadcasts.
// ---------------------------------------------------------------------------
__device__ __forceinline__ void bwd_comp16(const uv4* buf, const float (*W)[4096],
                                           int woff, int koff, float acc[4]) {
#pragma unroll
    for (int i = 0; i < 16; ++i) {
        half8v hv = __builtin_bit_cast(half8v, buf[i]);
        float hf[8];
#pragma unroll
        for (int k = 0; k < 8; ++k) hf[k] = (float)hv[k];
        int k0 = woff + koff + i * 128;
#pragma unroll
        for (int r = 0; r < 4; ++r) {
            const float* wr = &W[r][k0];
            float4 wa = *(const float4*)wr;
            float4 wb = *(const float4*)(wr + 4);
            acc[r] += hf[0]*wa.x + hf[1]*wa.y + hf[2]*wa.z + hf[3]*wa.w
                    + hf[4]*wb.x + hf[5]*wb.y + hf[6]*wb.z + hf[7]*wb.w;
        }
    }
}

// ---------------------------------------------------------------------------
// Persistent pipelined BACKWARD. L1 group (wid<128): t1=511-s. L0 group:
// t0=512-s, fusing dh0_ext = dG1(t0) @ W_ih1^T. dG overwrites gates (sc0sc1);
// dc persistent in LDS. Signals wave-0-only after vmcnt(0).
// ---------------------------------------------------------------------------
__global__ __launch_bounds__(NTHR, 1) void bwd_persist(
    const float* __restrict__ WT_HH0, const float* __restrict__ WT_HH1,
    const float* __restrict__ WT_IH1, const float* __restrict__ W_out,
    h16* __restrict__ G0, h16* __restrict__ G1,
    const h16* __restrict__ C0h, const h16* __restrict__ C1h,
    int* __restrict__ cntB0, int* __restrict__ cntB1)
{
    __shared__ float Wlds[4][4096];      // 64KB fp32 (L1 uses cols 0..2047)
    __shared__ float red[8][4][32];      // 4KB
    __shared__ float dc_l[4][32];        // persistent dc
    __shared__ h16   dg_s[16][32];
    __shared__ float wout_l[4];

    const int tid = threadIdx.x, wid = blockIdx.x;
    const bool isL1 = (wid >> 7) == 0;
    const int rslot = wid & 127, j0 = rslot * 4;
    const int wv = tid >> 6, lane = tid & 63, b = lane & 31, half = lane >> 5;
    const int koff = wv * 16 + half * 8;         // h16 index, 16 distinct values

    if (isL1) {
        for (int idx = tid; idx < 2048; idx += NTHR) {   // 4 rows x 512 float4
            int jr = idx >> 9, c4 = idx & 511;
            *(float4*)&Wlds[jr][c4 * 4] = *(const float4*)(WT_HH1 + (size_t)(j0 + jr) * G4 + c4 * 4);
        }
        if (tid < 4) wout_l[tid] = W_out[j0 + tid];
    } else {
        for (int idx = tid; idx < 4096; idx += NTHR) {   // 4 rows x 1024 float4
            int jr = idx >> 10, c4 = idx & 1023;
            if (c4 < 512)
                *(float4*)&Wlds[jr][c4 * 4] = *(const float4*)(WT_HH0 + (size_t)(j0 + jr) * G4 + c4 * 4);
            else
                *(float4*)&Wlds[jr][2048 + (c4 - 512) * 4] =
                    *(const float4*)(WT_IH1 + (size_t)(j0 + jr) * G4 + (c4 - 512) * 4);
        }
    }
    __syncthreads();

#pragma unroll 1
    for (int s = 0; s <= TT; ++s) {
        if (s > 0) {
            wait_ge(cntB1 + (size_t)(s - 1) * CSTR, 128);
            if (!isL1) wait_ge(cntB0 + (size_t)(s - 1) * CSTR, 128);
        }
        const int t = isL1 ? (511 - s) : (512 - s);
        const bool active = isL1 ? (s < TT) : (s >= 1);
        const bool haveDot = active && !(isL1 && t == 511);
        if (active) {
            if (haveDot) {
                float acc[4] = {0.f, 0.f, 0.f, 0.f};
                if (isL1) {
                    uv4 buf[16];
                    const char* p = (const char*)(G1 + (size_t)(t + 1) * BG + (size_t)b * G4) + koff * 2;
                    dc_issue8(p, buf);
                    dc_issue8(p + 2048, buf + 8);
                    vm_wait0();
                    bwd_comp16(buf, Wlds, 0, koff, acc);
                } else {
                    uv4 buf[16];
                    const bool hasA = (t < 511);
                    if (hasA) {
                        const char* pa = (const char*)(G0 + (size_t)(t + 1) * BG + (size_t)b * G4) + koff * 2;
                        dc_issue8(pa, buf);
                        dc_issue8(pa + 2048, buf + 8);
                        vm_wait0();
                        bwd_comp16(buf, Wlds, 0, koff, acc);
                    }
                    const char* pb = (const char*)(G1 + (size_t)t * BG + (size_t)b * G4) + koff * 2;
                    dc_issue8(pb, buf);
                    dc_issue8(pb + 2048, buf + 8);
                    vm_wait0();
                    bwd_comp16(buf, Wlds, 2048, koff, acc);
                }
#pragma unroll
                for (int jr = 0; jr < 4; ++jr) acc[jr] += __shfl_xor(acc[jr], 32);
#pragma unroll
                for (int rr = 0; rr < 2; ++rr) {
                    int jr = half * 2 + rr;
                    red[wv][jr][b] = acc[jr];
                }
            }
            __syncthreads();
            if (tid < 128) {   // pointwise: (jr, b)
                int jr = tid >> 5, bb = tid & 31;
                int j = j0 + jr;
                float dh = 0.f;
                if (haveDot) {
#pragma unroll
                    for (int w = 0; w < 8; ++w) dh += red[w][jr][bb];
                }
                if (isL1) dh += wout_l[jr];
                const h16* Gt = (isL1 ? G1 : G0) + (size_t)t * BG + bb * G4;
                const h16* Ch = isL1 ? C1h : C0h;
                float i_ = (float)Gt[j];
                float f_ = (float)Gt[HH + j];
                float g_ = (float)Gt[2 * HH + j];
                float o_ = (float)Gt[3 * HH + j];
                float c  = (float)Ch[(size_t)t * BH + bb * HH + j];
                float cp = (t > 0) ? (float)Ch[(size_t)(t - 1) * BH + bb * HH + j] : 0.f;
                float th = tanhf(c);
                float dc_in = (t < 511) ? dc_l[jr][bb] : 0.f;
                float do_ = dh * th;
                float dc = dc_in + dh * o_ * (1.f - th * th);
                float di = dc * g_, df = dc * cp, dg = dc * i_;
                dg_s[0 * 4 + jr][bb] = (h16)(di * i_ * (1.f - i_));
                dg_s[1 * 4 + jr][bb] = (h16)(df * f_ * (1.f - f_));
                dg_s[2 * 4 + jr][bb] = (h16)(dg * (1.f - g_ * g_));
                dg_s[3 * 4 + jr][bb] = (h16)(do_ * o_ * (1.f - o_));
                dc_l[jr][bb] = dc * f_;
            }
            __syncthreads();
            if (tid < 64) {    // dG pack+store: wave 0 ONLY (2 per lane), sc0sc1
                h16* Gw = (isL1 ? G1 : G0) + (size_t)t * BG;
#pragma unroll
                for (int rep = 0; rep < 2; ++rep) {
                    int idx = tid + rep * 64;
                    int q = idx >> 5, bb = idx & 31;
                    half4v hp = {dg_s[q * 4 + 0][bb], dg_s[q * 4 + 1][bb],
                                 dg_s[q * 4 + 2][bb], dg_s[q * 4 + 3][bb]};
                    st8_dc(Gw + (size_t)bb * G4 + q * HH + j0, __builtin_bit_cast(uv2, hp));
                }
            }
            vm_wait0();        // wave0: dG stores at MALL before the signal
        }
        if (s < TT && tid == 0) atomicAdd((isL1 ? cntB1 : cntB0) + (size_t)s * CSTR, 1);
    }
}

// ---------------------------------------------------------------------------
extern "C" void kernel_launch(void* const* d_in, const int* in_sizes, int n_in,
                              void* d_out, int out_size, void* d_ws, size_t ws_size,
                              hipStream_t stream) {
    const float* x     = (const float*)d_in[0];
    const float* W_ih0 = (const float*)d_in[1];
    const float* W_hh0 = (const float*)d_in[2];
    const float* b_ih0 = (const float*)d_in[3];
    const float* b_hh0 = (const float*)d_in[4];
    const float* W_ih1 = (const float*)d_in[5];
    const float* W_hh1 = (const float*)d_in[6];
    const float* b_ih1 = (const float*)d_in[7];
    const float* b_hh1 = (const float*)d_in[8];
    const float* W_out = (const float*)d_in[9];
    float* out = (float*)d_out;

    // ---- workspace layout (~180 MB) ----
    char* p = (char*)d_ws;
    auto alloc = [&](size_t bytes) { char* r = p; p += (bytes + 255) & ~(size_t)255; return r; };
    h16*  G0     = (h16*)alloc((size_t)TT * BG * 2);   // xg0 -> gates0 -> dG0
    h16*  G1     = (h16*)alloc((size_t)TT * BG * 2);   // gates1 -> dG1
    h16*  C0h    = (h16*)alloc((size_t)TT * BH * 2);
    h16*  C1h    = (h16*)alloc((size_t)TT * BH * 2);
    float* H0p   = (float*)alloc((size_t)2 * BH * 4);  // fp32 ping-pong
    float* H1p   = (float*)alloc((size_t)2 * BH * 4);
    float* XT     = (float*)alloc((size_t)TT * BB * NIN * 4);
    float* WT_IH0 = (float*)alloc((size_t)NIN * G4 * 4);
    float* WT_HH0 = (float*)alloc((size_t)HH * G4 * 4);
    float* WT_HH1 = (float*)alloc((size_t)HH * G4 * 4);
    float* WT_IH1 = (float*)alloc((size_t)HH * G4 * 4);
    int*   cntF   = (int*)alloc((size_t)TT * CSTR * 4);
    int*   cntB0  = (int*)alloc((size_t)TT * CSTR * 4);
    int*   cntB1  = (int*)alloc((size_t)TT * CSTR * 4);
    if ((size_t)(p - (char*)d_ws) > ws_size) return;   // visible failure if ws too small

    hipMemsetAsync(cntF, 0, (size_t)3 * TT * CSTR * 4, stream);

    dim3 tb(32, 8);
    permute_x_k<<<1024, 256, 0, stream>>>(x, XT);
    transpose_k<<<dim3(NIN / 32, G4 / 32), tb, 0, stream>>>(W_ih0, WT_IH0, G4, NIN);
    transpose_k<<<dim3(HH / 32, G4 / 32), tb, 0, stream>>>(W_hh0, WT_HH0, G4, HH);
    transpose_k<<<dim3(HH / 32, G4 / 32), tb, 0, stream>>>(W_hh1, WT_HH1, G4, HH);
    transpose_k<<<dim3(HH / 32, G4 / 32), tb, 0, stream>>>(W_ih1, WT_IH1, G4, HH);

    // xg0 = XT @ W_ih0^T + b_ih0 + b_hh0   [16384 x 2048], K=64 (out fp16)
    gemm_k<float, h16><<<dim3(TT * BB / GBM, G4 / GBN), 256, 0, stream>>>(
        XT, WT_IH0, G0, TT * BB, G4, NIN, b_ih0, b_hh0, 0);

    fwd_persist<<<NWG, NTHR, 0, stream>>>(
        W_hh0, W_ih1, W_hh1, b_ih1, b_hh1,
        G0, G1, C0h, C1h, H0p, H1p, cntF);

    bwd_persist<<<NWG, NTHR, 0, stream>>>(
        WT_HH0, WT_HH1, WT_IH1, W_out,
        G0, G1, C0h, C1h, cntB0, cntB1);

    // dx = dG0 @ W_ih0  [16384 x 64], K=2048 -> scatter to out [B][T][NIN]
    gemm_k<h16, float><<<dim3(TT * BB / GBM, NIN / GBN), 256, 0, stream>>>(
        G0, W_ih0, out, TT * BB, NIN, G4, nullptr, nullptr, 1);
}